// Round 1
// baseline (94.594 us; speedup 1.0000x reference)
//
#include <hip/hip_runtime.h>
#include <math.h>

#define B_    8
#define S_    128
#define K_    12
#define DAR_  256
#define DENC_ 256
#define NNEG_ 128
#define W_    116          // S - K
#define BW_   928          // B * W

typedef __attribute__((ext_vector_type(8))) short short8;   // 8 bf16 (4 VGPRs)
typedef __attribute__((ext_vector_type(4))) float floatx4;  // MFMA C/D
typedef __attribute__((ext_vector_type(4))) unsigned short ushort4_t; // 4 bf16 (8B)

static __device__ __forceinline__ unsigned short f2bf(float f) {
    union { float f; unsigned int u; } v; v.f = f;
    return (unsigned short)((v.u + 0x7FFFu + ((v.u >> 16) & 1u)) >> 16);  // RNE
}

// ---------------------------------------------------------------------------
// Cast enc / cFeat / Wpred to bf16 in one pass. 163840 chunks of 8 floats.
// ---------------------------------------------------------------------------
__global__ __launch_bounds__(256) void cast_all(
    const float* __restrict__ enc, const float* __restrict__ cf,
    const float* __restrict__ wp,
    unsigned short* __restrict__ ench, unsigned short* __restrict__ cfh,
    unsigned short* __restrict__ wph)
{
    const int g = blockIdx.x * 256 + threadIdx.x;   // 0..163839
    const float* src; unsigned short* dst; int off;
    if (g < 32768)      { src = enc; dst = ench; off = g * 8; }
    else if (g < 65536) { src = cf;  dst = cfh;  off = (g - 32768) * 8; }
    else                { src = wp;  dst = wph;  off = (g - 65536) * 8; }
    float4 v0 = *(const float4*)(src + off);
    float4 v1 = *(const float4*)(src + off + 4);
    uint4 o;
    o.x = f2bf(v0.x) | ((unsigned)f2bf(v0.y) << 16);
    o.y = f2bf(v0.z) | ((unsigned)f2bf(v0.w) << 16);
    o.z = f2bf(v1.x) | ((unsigned)f2bf(v1.y) << 16);
    o.w = f2bf(v1.z) | ((unsigned)f2bf(v1.w) << 16);
    *(uint4*)(dst + off) = o;
}

// ---------------------------------------------------------------------------
// Stage 1 (MFMA): locC[k][bw][e] = sum_d c[bw][d] * Wp[k][e][d], bf16 out.
// B (Wpred 64-row tile) staged in LDS (reused by all 4 waves); A fragments
// loaded DIRECTLY from global (each is 8 contiguous bf16 = one uint4).
// OPERAND SWAP: mfma(Wp_frag, c_frag) -> D row = e, col = bw. Each lane then
// holds 4 CONTIGUOUS e values per sub-tile -> 8B vector stores (was 16 scalar
// ushort stores per lane).
// ---------------------------------------------------------------------------
__global__ __launch_bounds__(256) void stage1_mfma(
    const unsigned short* __restrict__ cfh,   // (B,S,256) bf16
    const unsigned short* __restrict__ wph,   // (K,256,256) bf16
    unsigned short* __restrict__ locCh)       // (K,BW,256) bf16
{
    __shared__ unsigned short Bh[64 * 256];   // 32 KB, swizzled

    const int tid = threadIdx.x;
    const int mt = blockIdx.x;                // 15 bw-tiles (last partial)
    const int nt = blockIdx.y;                // 4 e-tiles
    const int k  = blockIdx.z;                // 12

    const int lane = tid & 63, wv = tid >> 6;
    const int l15 = lane & 15, quad = lane >> 4;

    // ---- c-feature fragments direct from global (issue before B staging).
    // Invalid rows (am >= BW) clamp to a valid row; they become unused D
    // columns, masked at the store.
    const int am = mt * 64 + wv * 16 + l15;   // bw row
    const bool avalid = (am < BW_);
    const int amc = avalid ? am : (BW_ - 1);
    const int b = amc / W_, w = amc - b * W_;
    const unsigned short* arow = cfh + (size_t)(b * S_ + w) * 256;
    short8 a[8];
#pragma unroll
    for (int kt = 0; kt < 8; ++kt)
        a[kt] = *(const short8*)(arow + kt * 32 + quad * 8);

    // ---- B staging: 64 rows x 32 chunks = 2048, 8 per thread ----
#pragma unroll
    for (int i = 0; i < 8; ++i) {
        const int flat = i * 256 + tid;
        const int row = flat >> 5, ch = flat & 31;
        const int e = nt * 64 + row;
        uint4 bv = *(const uint4*)(wph + ((size_t)(k * 256 + e) * 256 + ch * 8));
        *(uint4*)&Bh[(row * 32 + (ch ^ (row & 7))) * 8] = bv;
    }
    __syncthreads();

    floatx4 acc[4];
#pragma unroll
    for (int n4 = 0; n4 < 4; ++n4) {
        floatx4 c = {0.f, 0.f, 0.f, 0.f};
        const int bn = n4 * 16 + l15;         // e row within 64-tile
#pragma unroll
        for (int kt = 0; kt < 8; ++kt) {
            const int ch = kt * 4 + quad;
            short8 bfrag = *(const short8*)&Bh[(bn * 32 + (ch ^ (bn & 7))) * 8];
            // swapped: A-op = Wp (rows = e), B-op = c (cols = bw)
            c = __builtin_amdgcn_mfma_f32_16x16x32_bf16(bfrag, a[kt], c, 0, 0, 0);
        }
        acc[n4] = c;
    }

    // D (swapped): row(e within subtile) = quad*4 + r, col(bw) = l15.
    // Lane owns 4 consecutive e -> one 8B store per sub-tile.
    if (avalid) {
        unsigned short* crow = locCh + ((size_t)k * BW_ + am) * 256;
#pragma unroll
        for (int n4 = 0; n4 < 4; ++n4) {
            ushort4_t o;
#pragma unroll
            for (int r = 0; r < 4; ++r) o[r] = f2bf(acc[n4][r]);
            *(ushort4_t*)(crow + nt * 64 + n4 * 16 + quad * 4) = o;
        }
    }
}

// ---------------------------------------------------------------------------
// Stage 2 (MFMA): block per (b,w). NO A/B LDS staging — fragments loaded
// directly from global (locC rows, gathered enc rows). LDS is only the 140
// row indices + the 12x132 logit table (~7 KB -> high occupancy).
// OPERAND SWAP: mfma(enc_frag, locC_frag) -> D row = n, col = k. Each lane
// then holds 4 contiguous n for one k -> float4 LDS writes (was 12 scalar).
// ---------------------------------------------------------------------------
__global__ __launch_bounds__(256) void stage2_mfma(
    const unsigned short* __restrict__ ench,   // (B,S,256) bf16
    const unsigned short* __restrict__ locCh,  // (K,BW,256) bf16
    const int* __restrict__ batchIdx,
    const int* __restrict__ seqIdx,
    float* __restrict__ part)                  // (2K, BW)
{
    __shared__ int   idxL[144];
    __shared__ float sc[K_ * 132];   // [0..127]=neg, [128]=pos

    const int tid = threadIdx.x;
    const int bw = blockIdx.x;                 // 0..927
    const int b = bw / W_, w = bw - b * W_;

    const int lane = tid & 63, wv = tid >> 6;
    const int l15 = lane & 15, quad = lane >> 4;

    // ---- locC fragments direct from global (independent of idxL) ----
    const int m = (l15 < K_) ? l15 : (K_ - 1);   // cols 12..15 dup k=11 (ignored)
    const unsigned short* arow = locCh + ((size_t)m * BW_ + bw) * 256;
    short8 a[8];
#pragma unroll
    for (int kt = 0; kt < 8; ++kt)
        a[kt] = *(const short8*)(arow + kt * 32 + quad * 8);

    // ---- row indices ----
    if (tid < NNEG_) {
        const int ii = (b * NNEG_ + tid) * W_ + w;
        const int bi = batchIdx[ii];
        int si = seqIdx[ii] + w;               // seqIdx in [1,S), w <= 115 -> < 243
        if (si >= S_) si -= S_;
        idxL[tid] = bi * S_ + si;
    } else if (tid < 140) {
        idxL[tid] = b * S_ + w + 1 + (tid - 128);   // positives k=0..11
    }
    __syncthreads();

    // ---- 9 N-tiles over 4 waves (wv, wv+4, wv+8); B frags direct gather ----
    floatx4 accT[3];
#pragma unroll
    for (int u = 0; u < 3; ++u) {
        const int t = wv + u * 4;
        floatx4 c = {0.f, 0.f, 0.f, 0.f};
        if (t < 9) {
            const int n = t * 16 + l15;
            const int nn = (n < 140) ? n : 128;    // pad rows dup idx 128 (unused)
            const unsigned short* brow = ench + (size_t)idxL[nn] * 256;
#pragma unroll
            for (int kt = 0; kt < 8; ++kt) {
                short8 bfrag = *(const short8*)(brow + kt * 32 + quad * 8);
                // swapped: A-op = enc rows (rows = n), B-op = locC (cols = k)
                c = __builtin_amdgcn_mfma_f32_16x16x32_bf16(bfrag, a[kt], c, 0, 0, 0);
            }
        }
        accT[u] = c;
    }

    const float inv = 1.0f / 256.0f;
#pragma unroll
    for (int u = 0; u < 3; ++u) {
        const int t = wv + u * 4;
        if (t < 9 && l15 < K_) {               // col = k = l15
            if (t < 8) {
                // rows n = t*16 + quad*4 + r, r=0..3 -> contiguous float4
                float4 v = make_float4(accT[u][0] * inv, accT[u][1] * inv,
                                       accT[u][2] * inv, accT[u][3] * inv);
                *(float4*)&sc[l15 * 132 + t * 16 + quad * 4] = v;
            } else {
                // pos tile: n = 128 + quad*4 + r is the positive for k'=quad*4+r;
                // keep only the diagonal element (k' == l15).
#pragma unroll
                for (int r = 0; r < 4; ++r)
                    if (l15 == quad * 4 + r)
                        sc[l15 * 132 + 128] = accT[u][r] * inv;
            }
        }
    }
    __syncthreads();

    // ---- LSE + acc per k (wave wv: k = wv, wv+4, wv+8) ----
    for (int k = wv; k < K_; k += 4) {
        const float x0  = sc[k * 132 + lane];        // neg 0..63
        const float x1  = sc[k * 132 + 64 + lane];   // neg 64..127
        const float pos = sc[k * 132 + 128];
        float mn = fmaxf(x0, x1);
#pragma unroll
        for (int o = 1; o < 64; o <<= 1) mn = fmaxf(mn, __shfl_xor(mn, o, 64));
        const float m2 = fmaxf(mn, pos);
        float s = __expf(x0 - m2) + __expf(x1 - m2);
#pragma unroll
        for (int o = 1; o < 64; o <<= 1) s += __shfl_xor(s, o, 64);
        if (lane == 0) {
            const float lse = m2 + __logf(s + __expf(pos - m2));
            part[k * BW_ + bw]        = lse - pos;
            part[(K_ + k) * BW_ + bw] = (pos >= mn) ? 1.0f : 0.0f;
        }
    }
}

// ---------------------------------------------------------------------------
// Stage 3: reduce (2K, BW) partials to the 24 outputs.
// ---------------------------------------------------------------------------
__global__ __launch_bounds__(256) void stage3_reduce(
    const float* __restrict__ part, float* __restrict__ out)
{
    __shared__ float wsum[4];
    const int o = blockIdx.x, tid = threadIdx.x;
    float s = 0.f;
    for (int i = tid; i < BW_; i += 256) s += part[o * BW_ + i];
#pragma unroll
    for (int off = 1; off < 64; off <<= 1) s += __shfl_xor(s, off, 64);
    if ((tid & 63) == 0) wsum[tid >> 6] = s;
    __syncthreads();
    if (tid == 0)
        out[o] = (wsum[0] + wsum[1] + wsum[2] + wsum[3]) / (float)BW_;
}

// ---------------------------------------------------------------------------
extern "C" void kernel_launch(void* const* d_in, const int* in_sizes, int n_in,
                              void* d_out, int out_size, void* d_ws, size_t ws_size,
                              hipStream_t stream) {
    const float* cFeat    = (const float*)d_in[0];
    const float* enc      = (const float*)d_in[1];
    const float* Wp       = (const float*)d_in[2];
    const int*   batchIdx = (const int*)d_in[3];
    const int*   seqIdx   = (const int*)d_in[4];
    float* out = (float*)d_out;

    unsigned short* ench  = (unsigned short*)d_ws;            // 262144 bf16
    unsigned short* cfh   = ench + 262144;                    // 262144 bf16
    unsigned short* wph   = cfh + 262144;                     // 786432 bf16
    unsigned short* locCh = wph + 786432;                     // K*BW*256 bf16
    float*          part  = (float*)(locCh + (size_t)K_ * BW_ * 256);  // (2K,BW)

    hipLaunchKernelGGL(cast_all, dim3(640), dim3(256), 0, stream,
                       enc, cFeat, Wp, ench, cfh, wph);
    hipLaunchKernelGGL(stage1_mfma, dim3(15, 4, 12), dim3(256), 0, stream,
                       cfh, wph, locCh);
    hipLaunchKernelGGL(stage2_mfma, dim3(BW_), dim3(256), 0, stream,
                       ench, locCh, batchIdx, seqIdx, part);
    hipLaunchKernelGGL(stage3_reduce, dim3(24), dim3(256), 0, stream,
                       part, out);
}